// Round 3
// baseline (329.592 us; speedup 1.0000x reference)
//
#include <hip/hip_runtime.h>
#include <math.h>

#define BQ 64
#define TBI 3000
#define DBI 128
#define TSW 375
#define TS1 188
#define DSW 192
#define NF 300
#define DMODEL 512
#define EPSLN 1e-5f

typedef __bf16 bf16x8 __attribute__((ext_vector_type(8)));
typedef float f32x4 __attribute__((ext_vector_type(4)));

__device__ __forceinline__ unsigned short f2bf(float f) {
    unsigned u = __float_as_uint(f);
    unsigned r = (u + 0x7FFFu + ((u >> 16) & 1u)) >> 16;
    return (unsigned short)r;
}

// ---------------- Kernel A: conv->LN->dot->sigmoid => alpha [B,T]; 2 rows/wave, float4 loads
__global__ __launch_bounds__(256) void k_alpha2(
    const float* __restrict__ fs, const float* __restrict__ conv_w,
    const float* __restrict__ ln_g, const float* __restrict__ ln_b,
    const float* __restrict__ wp_w, const float* __restrict__ wp_b,
    float* __restrict__ alpha_out)
{
    int wave = threadIdx.x >> 6, lane = threadIdx.x & 63;
    int l = lane & 31;                                  // position within row
    long g = (long)blockIdx.x * 8 + wave * 2 + (lane >> 5);
    const float* row = fs + g * DBI;
    float4 f  = *(const float4*)&row[4 * l];
    float4 cw = *(const float4*)&conv_w[4 * l];
    float4 x; x.x = f.x * cw.x; x.y = f.y * cw.y; x.z = f.z * cw.z; x.w = f.w * cw.w;
    float s = x.x + x.y + x.z + x.w;
    for (int m = 16; m >= 1; m >>= 1) s += __shfl_xor(s, m, 64);
    float mu = s * (1.0f / 128.0f);
    float4 d; d.x = x.x - mu; d.y = x.y - mu; d.z = x.z - mu; d.w = x.w - mu;
    float q = d.x * d.x + d.y * d.y + d.z * d.z + d.w * d.w;
    for (int m = 16; m >= 1; m >>= 1) q += __shfl_xor(q, m, 64);
    float var = q * (1.0f / 128.0f);
    float rs = rsqrtf(var + EPSLN);
    float4 lg = *(const float4*)&ln_g[4 * l];
    float4 lb = *(const float4*)&ln_b[4 * l];
    float4 wp = *(const float4*)&wp_w[4 * l];
    float z = (d.x * rs * lg.x + lb.x) * wp.x + (d.y * rs * lg.y + lb.y) * wp.y
            + (d.z * rs * lg.z + lb.z) * wp.z + (d.w * rs * lg.w + lb.w) * wp.w;
    for (int m = 16; m >= 1; m >>= 1) z += __shfl_xor(z, m, 64);
    z += wp_b[0];
    float a = 4.0f / (1.0f + expf(-z));
    if (l == 0) alpha_out[g] = a;
}

// ---------------- Kernel B: per-batch sums (f64) + scan + searchsorted, fused
__global__ __launch_bounds__(1024) void k_scan2(
    const float* __restrict__ alpha, const int* __restrict__ tlen,
    float2* __restrict__ params, float* __restrict__ qtyb,
    float2* __restrict__ c2, float* __restrict__ tcont)
{
    __shared__ float2 sc[TBI];           // .x = cumsum(alpha_cif/thr) ; .y = cumsum(alpha_cif)
    __shared__ float2 part[2][1024];
    __shared__ double red[1024];
    int b = blockIdx.x, tid = threadIdx.x;
    const float* ar = alpha + (long)b * TBI;
    double s = 0.0;
    for (int t = tid; t < TBI; t += 1024) s += (double)ar[t];
    red[tid] = s; __syncthreads();
    for (int d = 512; d >= 1; d >>= 1) { if (tid < d) red[tid] += red[tid + d]; __syncthreads(); }
    double sum_a = red[0]; __syncthreads();
    double tgt = (double)tlen[b];
    double sa = sum_a < 1e-8 ? 1e-8 : sum_a;
    float r = (float)(tgt / sa);
    double s2 = 0.0;
    for (int t = tid; t < TBI; t += 1024) s2 += (double)(ar[t] * r);
    red[tid] = s2; __syncthreads();
    for (int d = 512; d >= 1; d >>= 1) { if (tid < d) red[tid] += red[tid + d]; __syncthreads(); }
    float sum_cif = (float)red[0];
    float cs = ceilf(sum_cif); if (cs < 1.0f) cs = 1.0f;
    float thr = sum_cif / cs;
    float rthr = 1.0f / thr;             // exact here (thr == 1.0)
    if (tid == 0) { params[b] = make_float2(r, thr); qtyb[b] = (float)fabs(sum_a - tgt); }
    // scan
    int base = tid * 3;
    float2 run = make_float2(0.f, 0.f);
    if (base < TBI) {
        for (int j = 0; j < 3; ++j) {
            int t = base + j;
            float ac = ar[t] * r;
            run.x += ac * rthr; run.y += ac;
            sc[t] = run;
        }
    }
    part[0][tid] = (base < TBI) ? run : make_float2(0.f, 0.f);
    __syncthreads();
    int srcb = 0;
    for (int d = 1; d < 1024; d <<= 1) {
        float2 v = part[srcb][tid];
        if (tid >= d) { float2 u = part[srcb][tid - d]; v.x += u.x; v.y += u.y; }
        part[srcb ^ 1][tid] = v;
        srcb ^= 1;
        __syncthreads();
    }
    if (base < TBI && tid > 0) {
        float2 off = part[srcb][tid - 1];
        for (int j = 0; j < 3; ++j) { sc[base + j].x += off.x; sc[base + j].y += off.y; }
    }
    __syncthreads();
    for (int t = tid; t < TBI; t += 1024) {
        float ac = ar[t] * r;
        c2[(long)b * TBI + t] = make_float2(sc[t].x, ac);
    }
    if (tid < NF) {
        float v = (float)(tid + 1) * thr;
        int lo = 0, hi = TBI;
        while (lo < hi) { int mid = (lo + hi) >> 1; if (sc[mid].y < v) lo = mid + 1; else hi = mid; }
        int ff = lo; if (ff > TBI - 1) ff = TBI - 1;
        int tl = ff - 1; if (tl < 0) tl = 0;
        float cum_at = sc[tl].y;
        float a_at = ar[ff] * r;
        if (a_at < 1e-8f) a_at = 1e-8f;
        float tc = (float)tl + (v - cum_at) / a_at;
        tc = fminf(fmaxf(tc, 0.0f), (float)(TBI - 1));
        tcont[b * NF + tid] = tc;
    }
}

// ---------------- Kernel B2: qty_loss = mean over batches
__global__ void k_qty(const float* __restrict__ qtyb, float* __restrict__ out)
{
    float v = qtyb[threadIdx.x & 63];
    for (int m = 32; m >= 1; m >>= 1) v += __shfl_xor(v, m, 64);
    if (threadIdx.x == 0) out[0] = v * (1.0f / (float)BQ);
}

// ---------------- Kernel D: CIF scatter-integrate, float2 loads + next-frame prefetch
#define FPW 94
__global__ __launch_bounds__(256) void k_cif2(
    const float* __restrict__ fs, const float2* __restrict__ c2,
    const float2* __restrict__ params, float* __restrict__ at)
{
    int wid = threadIdx.x >> 6, lane = threadIdx.x & 63;
    int wg = blockIdx.x * 4 + wid;
    int b = wg >> 5, slot = wg & 31;
    int t0 = slot * FPW;
    int t1 = t0 + FPW; if (t1 > TBI) t1 = TBI;
    if (t0 >= t1) return;
    float thr = params[b].y;
    float rthr = 1.0f / thr;
    const float2* cb = c2 + (long)b * TBI;
    const float* fb = fs + (long)b * TBI * DBI;
    float* ab = at + (long)b * NF * DBI;
    int cur = -1;
    float a0 = 0.f, a1 = 0.f;
    float2 v = cb[t0];
    float2 h = *(const float2*)&fb[(long)t0 * DBI + 2 * lane];
    for (int t = t0; t < t1; ++t) {
        float2 vn = v, hn = h;
        if (t + 1 < t1) {
            vn = cb[t + 1];
            hn = *(const float2*)&fb[(long)(t + 1) * DBI + 2 * lane];
        }
        float c = v.x, ac = v.y;
        float av = ac * rthr;
        float prev = c - av;
        float kp = floorf(prev), kc = floorf(c);
        bool fired = kc > kp;
        float w_lo = fired ? (kp + 1.0f - prev) * thr : ac;
        float w_hi = fired ? (c - kc) * thr : 0.0f;
        int ip = (int)kp; if (ip > NF - 1) ip = NF - 1; if (ip < 0) ip = 0;
        int ic = (int)kc; if (ic > NF - 1) ic = NF - 1; if (ic < 0) ic = 0;
        if (ip != cur) {
            if (cur >= 0) { atomicAdd(&ab[cur * DBI + 2 * lane], a0); atomicAdd(&ab[cur * DBI + 2 * lane + 1], a1); }
            cur = ip; a0 = 0.f; a1 = 0.f;
        }
        a0 += w_lo * h.x; a1 += w_lo * h.y;
        if (fired) {
            if (ic != cur) {
                if (cur >= 0) { atomicAdd(&ab[cur * DBI + 2 * lane], a0); atomicAdd(&ab[cur * DBI + 2 * lane + 1], a1); }
                cur = ic; a0 = 0.f; a1 = 0.f;
            }
            a0 += w_hi * h.x; a1 += w_hi * h.y;
        }
        v = vn; h = hn;
    }
    if (cur >= 0) { atomicAdd(&ab[cur * DBI + 2 * lane], a0); atomicAdd(&ab[cur * DBI + 2 * lane + 1], a1); }
}

// ---------------- Prep: swizzle weights into MFMA B-fragment order (bf16)
__global__ __launch_bounds__(256) void k_prep(
    const float* __restrict__ f0w, const float* __restrict__ f1w,
    const float* __restrict__ tw, const float* __restrict__ aw, const float* __restrict__ bw,
    unsigned short* __restrict__ Wg, unsigned short* __restrict__ Wb,
    unsigned short* __restrict__ W2)
{
    int i = blockIdx.x * 256 + threadIdx.x;
    if (i < 49152) {                       // film gamma/beta: K=128 (KT=4), N=384 (NT=24)
        int j = i & 7, lane = (i >> 3) & 63, kt = (i >> 9) & 3, nt = i >> 11;
        int k = kt * 32 + (lane >> 4) * 8 + j;
        int n = nt * 16 + (lane & 15);
        float g, b;
        if (n < 192) { g = f0w[k * 384 + n];         b = f0w[k * 384 + n + 192]; }
        else         { g = f1w[k * 384 + (n - 192)]; b = f1w[k * 384 + (n - 192) + 192]; }
        Wg[i] = f2bf(g); Wb[i] = f2bf(b);
    } else if (i < 49152 + 262144) {       // W2 stacked [tw;aw;bw]: K=512 (KT=16), N=512 (NT=32)
        int ii = i - 49152;
        int j = ii & 7, lane = (ii >> 3) & 63, kt = (ii >> 9) & 15, nt = ii >> 13;
        int k = kt * 32 + (lane >> 4) * 8 + j;
        int n = nt * 16 + (lane & 15);
        float v;
        if (k < 128)      v = tw[k * 512 + n];
        else if (k < 320) v = aw[(k - 128) * 512 + n];
        else              v = bw[(k - 320) * 512 + n];
        W2[ii] = f2bf(v);
    }
}

__global__ void k_prepb(const float* __restrict__ f0b, const float* __restrict__ f1b,
                        const float* __restrict__ tb, const float* __restrict__ apb,
                        const float* __restrict__ bpb,
                        float* __restrict__ gbias, float* __restrict__ bbias,
                        float* __restrict__ bias2)
{
    int c = threadIdx.x;
    if (c < 384) {
        gbias[c] = c < 192 ? f0b[c] : f1b[c - 192];
        bbias[c] = c < 192 ? f0b[c + 192] : f1b[c - 192 + 192];
    }
    bias2[c] = tb[c] + apb[c] + bpb[c];
}

// ---------------- Kernel E (MFMA): FiLM + interp + projections; pipelined B-loads
#define ROWS 32
__global__ __launch_bounds__(256) void k_emb3(
    const float* __restrict__ at, const float* __restrict__ tcont,
    const float* __restrict__ src0, const float* __restrict__ src1,
    const unsigned short* __restrict__ Wg, const unsigned short* __restrict__ Wb,
    const unsigned short* __restrict__ W2,
    const float* __restrict__ gbias, const float* __restrict__ bbias,
    const float* __restrict__ bias2, float* __restrict__ embs)
{
    __shared__ __align__(16) unsigned short X[ROWS][520];
    __shared__ float s_w0[ROWS], s_w1[ROWS];
    __shared__ int s_lo0[ROWS], s_lo1[ROWS], s_b[ROWS];
    int tid = threadIdx.x;
    int wave = tid >> 6, lane = tid & 63;
    long r0 = (long)blockIdx.x * ROWS;
    for (int idx = tid; idx < ROWS * 32; idx += 256) {
        int r = idx >> 5, k4 = (idx & 31) * 4;
        float4 v = *(const float4*)&at[(r0 + r) * DBI + k4];
        X[r][k4 + 0] = f2bf(v.x); X[r][k4 + 1] = f2bf(v.y);
        X[r][k4 + 2] = f2bf(v.z); X[r][k4 + 3] = f2bf(v.w);
    }
    if (tid < ROWS) {
        long g = r0 + tid;
        s_b[tid] = (int)(g / NF);
        float tc = tcont[g];
        float t0 = tc * ((float)TSW / 3000.0f);
        int lo0 = (int)t0; if (lo0 > TSW - 2) lo0 = TSW - 2; if (lo0 < 0) lo0 = 0;
        s_lo0[tid] = lo0; s_w0[tid] = t0 - (float)lo0;
        float t1 = tc * ((float)TS1 / 3000.0f);
        int lo1 = (int)t1; if (lo1 > TS1 - 2) lo1 = TS1 - 2; if (lo1 < 0) lo1 = 0;
        s_lo1[tid] = lo1; s_w1[tid] = t1 - (float)lo1;
    }
    __syncthreads();
    int mrow = lane & 15, quad = lane >> 4;
    // ---- Phase 1: film GEMM (gamma+beta) + interp/FiLM epilogue -> X[:,128:512] bf16
    for (int nt = wave; nt < 24; nt += 4) {
        f32x4 ag0 = {0,0,0,0}, ag1 = {0,0,0,0}, ab0 = {0,0,0,0}, ab1 = {0,0,0,0};
        #pragma unroll
        for (int kt = 0; kt < 4; ++kt) {
            bf16x8 a0 = *(const bf16x8*)&X[mrow][kt * 32 + quad * 8];
            bf16x8 a1 = *(const bf16x8*)&X[16 + mrow][kt * 32 + quad * 8];
            bf16x8 bg = *(const bf16x8*)&Wg[(((nt * 4 + kt) * 64) + lane) * 8];
            bf16x8 bb = *(const bf16x8*)&Wb[(((nt * 4 + kt) * 64) + lane) * 8];
            ag0 = __builtin_amdgcn_mfma_f32_16x16x32_bf16(a0, bg, ag0, 0, 0, 0);
            ag1 = __builtin_amdgcn_mfma_f32_16x16x32_bf16(a1, bg, ag1, 0, 0, 0);
            ab0 = __builtin_amdgcn_mfma_f32_16x16x32_bf16(a0, bb, ab0, 0, 0, 0);
            ab1 = __builtin_amdgcn_mfma_f32_16x16x32_bf16(a1, bb, ab1, 0, 0, 0);
        }
        int c = nt * 16 + mrow;
        bool sel = c >= DSW;
        int cc = sel ? c - DSW : c;
        const float* S = sel ? src1 : src0;
        int Ts = sel ? TS1 : TSW;
        float gb = gbias[c], bbv = bbias[c];
        #pragma unroll
        for (int m = 0; m < 2; ++m) {
            #pragma unroll
            for (int q = 0; q < 4; ++q) {
                int r = m * 16 + quad * 4 + q;
                int b = s_b[r];
                int lo = sel ? s_lo1[r] : s_lo0[r];
                float w = sel ? s_w1[r] : s_w0[r];
                const float* Sp = S + ((long)b * Ts + lo) * DSW + cc;
                float pv = (1.0f - w) * Sp[0] + w * Sp[DSW];
                float gv = (m ? ag1[q] : ag0[q]) + gb;
                float bv = (m ? ab1[q] : ab0[q]) + bbv;
                X[r][128 + c] = f2bf(gv * pv + bv);
            }
        }
    }
    __syncthreads();
    // ---- Phase 2: embs[32,512] = X[32,512] @ W2[512,512] + bias2 ; B double-buffered
    f32x4 acc0[8], acc1[8];
    #pragma unroll
    for (int n = 0; n < 8; ++n) { acc0[n] = (f32x4){0,0,0,0}; acc1[n] = (f32x4){0,0,0,0}; }
    bf16x8 bcur[8];
    #pragma unroll
    for (int n = 0; n < 8; ++n)
        bcur[n] = *(const bf16x8*)&W2[(((wave * 8 + n) * 16 + 0) * 64 + lane) * 8];
    for (int kt = 0; kt < 16; ++kt) {
        bf16x8 bnxt[8];
        if (kt < 15) {
            #pragma unroll
            for (int n = 0; n < 8; ++n)
                bnxt[n] = *(const bf16x8*)&W2[(((wave * 8 + n) * 16 + kt + 1) * 64 + lane) * 8];
        }
        bf16x8 a0 = *(const bf16x8*)&X[mrow][kt * 32 + quad * 8];
        bf16x8 a1 = *(const bf16x8*)&X[16 + mrow][kt * 32 + quad * 8];
        #pragma unroll
        for (int n = 0; n < 8; ++n) {
            acc0[n] = __builtin_amdgcn_mfma_f32_16x16x32_bf16(a0, bcur[n], acc0[n], 0, 0, 0);
            acc1[n] = __builtin_amdgcn_mfma_f32_16x16x32_bf16(a1, bcur[n], acc1[n], 0, 0, 0);
        }
        #pragma unroll
        for (int n = 0; n < 8; ++n) bcur[n] = bnxt[n];
    }
    #pragma unroll
    for (int n = 0; n < 8; ++n) {
        int cbase = (wave * 8 + n) * 16 + mrow;
        float bv = bias2[cbase];
        #pragma unroll
        for (int q = 0; q < 4; ++q) {
            embs[(r0 + quad * 4 + q) * DMODEL + cbase] = acc0[n][q] + bv;
            embs[(r0 + 16 + quad * 4 + q) * DMODEL + cbase] = acc1[n][q] + bv;
        }
    }
}

extern "C" void kernel_launch(void* const* d_in, const int* in_sizes, int n_in,
                              void* d_out, int out_size, void* d_ws, size_t ws_size,
                              hipStream_t stream)
{
    const float* fs     = (const float*)d_in[0];
    const float* src0   = (const float*)d_in[1];
    const float* src1   = (const float*)d_in[2];
    const int*   tlen   = (const int*)d_in[3];
    const float* conv_w = (const float*)d_in[4];
    const float* ln_g   = (const float*)d_in[5];
    const float* ln_b   = (const float*)d_in[6];
    const float* wp_w   = (const float*)d_in[7];
    const float* wp_b   = (const float*)d_in[8];
    const float* f0w    = (const float*)d_in[9];
    const float* f0b    = (const float*)d_in[10];
    const float* f1w    = (const float*)d_in[11];
    const float* f1b    = (const float*)d_in[12];
    const float* tw     = (const float*)d_in[13];
    const float* tb     = (const float*)d_in[14];
    const float* aw     = (const float*)d_in[15];
    const float* apb    = (const float*)d_in[16];
    const float* bw     = (const float*)d_in[17];
    const float* bpb    = (const float*)d_in[18];

    float* embs  = (float*)d_out;
    float* alpha = embs + (long)BQ * NF * DMODEL;
    float* qtyo  = alpha + (long)BQ * TBI;

    char* ws = (char*)d_ws;
    size_t off = 0;
    float*  at     = (float*)(ws + off);  off += 9830400;
    float2* c2     = (float2*)(ws + off); off += 1536000;
    float*  tcont  = (float*)(ws + off);  off += 76800;
    float2* params = (float2*)(ws + off); off += 512;
    float*  qtyb   = (float*)(ws + off);  off += 256;
    unsigned short* Wg = (unsigned short*)(ws + off); off += 98304;
    unsigned short* Wb = (unsigned short*)(ws + off); off += 98304;
    unsigned short* W2 = (unsigned short*)(ws + off); off += 524288;
    float* gbias = (float*)(ws + off); off += 1536;
    float* bbias = (float*)(ws + off); off += 1536;
    float* bias2 = (float*)(ws + off); off += 2048;

    hipMemsetAsync(at, 0, (size_t)BQ * NF * DBI * sizeof(float), stream);
    k_prep<<<1216, 256, 0, stream>>>(f0w, f1w, tw, aw, bw, Wg, Wb, W2);
    k_prepb<<<1, 512, 0, stream>>>(f0b, f1b, tb, apb, bpb, gbias, bbias, bias2);
    k_alpha2<<<(BQ * TBI) / 8, 256, 0, stream>>>(fs, conv_w, ln_g, ln_b, wp_w, wp_b, alpha);
    k_scan2<<<BQ, 1024, 0, stream>>>(alpha, tlen, params, qtyb, c2, tcont);
    k_qty<<<1, 64, 0, stream>>>(qtyb, qtyo);
    k_cif2<<<512, 256, 0, stream>>>(fs, c2, params, at);
    k_emb3<<<(BQ * NF) / ROWS, 256, 0, stream>>>(at, tcont, src0, src1,
                                                 Wg, Wb, W2, gbias, bbias, bias2, embs);
}

// Round 4
// 297.417 us; speedup vs baseline: 1.1082x; 1.1082x over previous
//
#include <hip/hip_runtime.h>
#include <math.h>

#define BQ 64
#define TBI 3000
#define DBI 128
#define TSW 375
#define TS1 188
#define DSW 192
#define NF 300
#define DMODEL 512
#define EPSLN 1e-5f

typedef __bf16 bf16x8 __attribute__((ext_vector_type(8)));
typedef float f32x4 __attribute__((ext_vector_type(4)));

__device__ __forceinline__ unsigned short f2bf(float f) {
    unsigned u = __float_as_uint(f);
    unsigned r = (u + 0x7FFFu + ((u >> 16) & 1u)) >> 16;
    return (unsigned short)r;
}

// ---------------- Kernel A: conv->LN->dot->sigmoid => alpha [B,T]; 2 rows/wave, float4 loads
__global__ __launch_bounds__(256) void k_alpha2(
    const float* __restrict__ fs, const float* __restrict__ conv_w,
    const float* __restrict__ ln_g, const float* __restrict__ ln_b,
    const float* __restrict__ wp_w, const float* __restrict__ wp_b,
    float* __restrict__ alpha_out)
{
    int wave = threadIdx.x >> 6, lane = threadIdx.x & 63;
    int l = lane & 31;
    long g = (long)blockIdx.x * 8 + wave * 2 + (lane >> 5);
    const float* row = fs + g * DBI;
    float4 f  = *(const float4*)&row[4 * l];
    float4 cw = *(const float4*)&conv_w[4 * l];
    float4 x; x.x = f.x * cw.x; x.y = f.y * cw.y; x.z = f.z * cw.z; x.w = f.w * cw.w;
    float s = x.x + x.y + x.z + x.w;
    for (int m = 16; m >= 1; m >>= 1) s += __shfl_xor(s, m, 64);
    float mu = s * (1.0f / 128.0f);
    float4 d; d.x = x.x - mu; d.y = x.y - mu; d.z = x.z - mu; d.w = x.w - mu;
    float q = d.x * d.x + d.y * d.y + d.z * d.z + d.w * d.w;
    for (int m = 16; m >= 1; m >>= 1) q += __shfl_xor(q, m, 64);
    float var = q * (1.0f / 128.0f);
    float rs = rsqrtf(var + EPSLN);
    float4 lg = *(const float4*)&ln_g[4 * l];
    float4 lb = *(const float4*)&ln_b[4 * l];
    float4 wp = *(const float4*)&wp_w[4 * l];
    float z = (d.x * rs * lg.x + lb.x) * wp.x + (d.y * rs * lg.y + lb.y) * wp.y
            + (d.z * rs * lg.z + lb.z) * wp.z + (d.w * rs * lg.w + lb.w) * wp.w;
    for (int m = 16; m >= 1; m >>= 1) z += __shfl_xor(z, m, 64);
    z += wp_b[0];
    float a = 4.0f / (1.0f + expf(-z));
    if (l == 0) alpha_out[g] = a;
}

// ---------------- Kernel B: per-batch sums (f64) + scan + searchsorted, fused
__global__ __launch_bounds__(1024) void k_scan2(
    const float* __restrict__ alpha, const int* __restrict__ tlen,
    float2* __restrict__ params, float* __restrict__ qtyb,
    float2* __restrict__ c2, float* __restrict__ tcont)
{
    __shared__ float2 sc[TBI];
    __shared__ float2 part[2][1024];
    __shared__ double red[1024];
    int b = blockIdx.x, tid = threadIdx.x;
    const float* ar = alpha + (long)b * TBI;
    double s = 0.0;
    for (int t = tid; t < TBI; t += 1024) s += (double)ar[t];
    red[tid] = s; __syncthreads();
    for (int d = 512; d >= 1; d >>= 1) { if (tid < d) red[tid] += red[tid + d]; __syncthreads(); }
    double sum_a = red[0]; __syncthreads();
    double tgt = (double)tlen[b];
    double sa = sum_a < 1e-8 ? 1e-8 : sum_a;
    float r = (float)(tgt / sa);
    double s2 = 0.0;
    for (int t = tid; t < TBI; t += 1024) s2 += (double)(ar[t] * r);
    red[tid] = s2; __syncthreads();
    for (int d = 512; d >= 1; d >>= 1) { if (tid < d) red[tid] += red[tid + d]; __syncthreads(); }
    float sum_cif = (float)red[0];
    float cs = ceilf(sum_cif); if (cs < 1.0f) cs = 1.0f;
    float thr = sum_cif / cs;
    float rthr = 1.0f / thr;
    if (tid == 0) { params[b] = make_float2(r, thr); qtyb[b] = (float)fabs(sum_a - tgt); }
    int base = tid * 3;
    float2 run = make_float2(0.f, 0.f);
    if (base < TBI) {
        for (int j = 0; j < 3; ++j) {
            int t = base + j;
            float ac = ar[t] * r;
            run.x += ac * rthr; run.y += ac;
            sc[t] = run;
        }
    }
    part[0][tid] = (base < TBI) ? run : make_float2(0.f, 0.f);
    __syncthreads();
    int srcb = 0;
    for (int d = 1; d < 1024; d <<= 1) {
        float2 v = part[srcb][tid];
        if (tid >= d) { float2 u = part[srcb][tid - d]; v.x += u.x; v.y += u.y; }
        part[srcb ^ 1][tid] = v;
        srcb ^= 1;
        __syncthreads();
    }
    if (base < TBI && tid > 0) {
        float2 off = part[srcb][tid - 1];
        for (int j = 0; j < 3; ++j) { sc[base + j].x += off.x; sc[base + j].y += off.y; }
    }
    __syncthreads();
    for (int t = tid; t < TBI; t += 1024) {
        float ac = ar[t] * r;
        c2[(long)b * TBI + t] = make_float2(sc[t].x, ac);
    }
    if (tid < NF) {
        float v = (float)(tid + 1) * thr;
        int lo = 0, hi = TBI;
        while (lo < hi) { int mid = (lo + hi) >> 1; if (sc[mid].y < v) lo = mid + 1; else hi = mid; }
        int ff = lo; if (ff > TBI - 1) ff = TBI - 1;
        int tl = ff - 1; if (tl < 0) tl = 0;
        float cum_at = sc[tl].y;
        float a_at = ar[ff] * r;
        if (a_at < 1e-8f) a_at = 1e-8f;
        float tc = (float)tl + (v - cum_at) / a_at;
        tc = fminf(fmaxf(tc, 0.0f), (float)(TBI - 1));
        tcont[b * NF + tid] = tc;
    }
}

// ---------------- Kernel B2: qty_loss = mean over batches
__global__ void k_qty(const float* __restrict__ qtyb, float* __restrict__ out)
{
    float v = qtyb[threadIdx.x & 63];
    for (int m = 32; m >= 1; m >>= 1) v += __shfl_xor(v, m, 64);
    if (threadIdx.x == 0) out[0] = v * (1.0f / (float)BQ);
}

// ---------------- Kernel D: CIF scatter-integrate, float2 loads + next-frame prefetch
#define FPW 94
__global__ __launch_bounds__(256) void k_cif2(
    const float* __restrict__ fs, const float2* __restrict__ c2,
    const float2* __restrict__ params, float* __restrict__ at)
{
    int wid = threadIdx.x >> 6, lane = threadIdx.x & 63;
    int wg = blockIdx.x * 4 + wid;
    int b = wg >> 5, slot = wg & 31;
    int t0 = slot * FPW;
    int t1 = t0 + FPW; if (t1 > TBI) t1 = TBI;
    if (t0 >= t1) return;
    float thr = params[b].y;
    float rthr = 1.0f / thr;
    const float2* cb = c2 + (long)b * TBI;
    const float* fb = fs + (long)b * TBI * DBI;
    float* ab = at + (long)b * NF * DBI;
    int cur = -1;
    float a0 = 0.f, a1 = 0.f;
    float2 v = cb[t0];
    float2 h = *(const float2*)&fb[(long)t0 * DBI + 2 * lane];
    for (int t = t0; t < t1; ++t) {
        float2 vn = v, hn = h;
        if (t + 1 < t1) {
            vn = cb[t + 1];
            hn = *(const float2*)&fb[(long)(t + 1) * DBI + 2 * lane];
        }
        float c = v.x, ac = v.y;
        float av = ac * rthr;
        float prev = c - av;
        float kp = floorf(prev), kc = floorf(c);
        bool fired = kc > kp;
        float w_lo = fired ? (kp + 1.0f - prev) * thr : ac;
        float w_hi = fired ? (c - kc) * thr : 0.0f;
        int ip = (int)kp; if (ip > NF - 1) ip = NF - 1; if (ip < 0) ip = 0;
        int ic = (int)kc; if (ic > NF - 1) ic = NF - 1; if (ic < 0) ic = 0;
        if (ip != cur) {
            if (cur >= 0) { atomicAdd(&ab[cur * DBI + 2 * lane], a0); atomicAdd(&ab[cur * DBI + 2 * lane + 1], a1); }
            cur = ip; a0 = 0.f; a1 = 0.f;
        }
        a0 += w_lo * h.x; a1 += w_lo * h.y;
        if (fired) {
            if (ic != cur) {
                if (cur >= 0) { atomicAdd(&ab[cur * DBI + 2 * lane], a0); atomicAdd(&ab[cur * DBI + 2 * lane + 1], a1); }
                cur = ic; a0 = 0.f; a1 = 0.f;
            }
            a0 += w_hi * h.x; a1 += w_hi * h.y;
        }
        v = vn; h = hn;
    }
    if (cur >= 0) { atomicAdd(&ab[cur * DBI + 2 * lane], a0); atomicAdd(&ab[cur * DBI + 2 * lane + 1], a1); }
}

// ---------------- Prep: swizzle weights into MFMA B-fragment order (bf16)
__global__ __launch_bounds__(256) void k_prep(
    const float* __restrict__ f0w, const float* __restrict__ f1w,
    const float* __restrict__ tw, const float* __restrict__ aw, const float* __restrict__ bw,
    unsigned short* __restrict__ Wg, unsigned short* __restrict__ Wb,
    unsigned short* __restrict__ W2)
{
    int i = blockIdx.x * 256 + threadIdx.x;
    if (i < 49152) {
        int j = i & 7, lane = (i >> 3) & 63, kt = (i >> 9) & 3, nt = i >> 11;
        int k = kt * 32 + (lane >> 4) * 8 + j;
        int n = nt * 16 + (lane & 15);
        float g, b;
        if (n < 192) { g = f0w[k * 384 + n];         b = f0w[k * 384 + n + 192]; }
        else         { g = f1w[k * 384 + (n - 192)]; b = f1w[k * 384 + (n - 192) + 192]; }
        Wg[i] = f2bf(g); Wb[i] = f2bf(b);
    } else if (i < 49152 + 262144) {
        int ii = i - 49152;
        int j = ii & 7, lane = (ii >> 3) & 63, kt = (ii >> 9) & 15, nt = ii >> 13;
        int k = kt * 32 + (lane >> 4) * 8 + j;
        int n = nt * 16 + (lane & 15);
        float v;
        if (k < 128)      v = tw[k * 512 + n];
        else if (k < 320) v = aw[(k - 128) * 512 + n];
        else              v = bw[(k - 320) * 512 + n];
        W2[ii] = f2bf(v);
    }
}

__global__ void k_prepb(const float* __restrict__ f0b, const float* __restrict__ f1b,
                        const float* __restrict__ tb, const float* __restrict__ apb,
                        const float* __restrict__ bpb,
                        float* __restrict__ gbias, float* __restrict__ bbias,
                        float* __restrict__ bias2)
{
    int c = threadIdx.x;
    if (c < 384) {
        gbias[c] = c < 192 ? f0b[c] : f1b[c - 192];
        bbias[c] = c < 192 ? f0b[c + 192] : f1b[c - 192 + 192];
    }
    bias2[c] = tb[c] + apb[c] + bpb[c];
}

// ---------------- Kernel E (MFMA): FiLM + interp + projections; 8 waves/block
#define ROWS 32
__global__ __launch_bounds__(512) void k_emb4(
    const float* __restrict__ at, const float* __restrict__ tcont,
    const float* __restrict__ src0, const float* __restrict__ src1,
    const unsigned short* __restrict__ Wg, const unsigned short* __restrict__ Wb,
    const unsigned short* __restrict__ W2,
    const float* __restrict__ gbias, const float* __restrict__ bbias,
    const float* __restrict__ bias2, float* __restrict__ embs)
{
    __shared__ __align__(16) unsigned short X[ROWS][520];
    __shared__ float s_w0[ROWS], s_w1[ROWS];
    __shared__ int s_lo0[ROWS], s_lo1[ROWS], s_b[ROWS];
    int tid = threadIdx.x;
    int wave = tid >> 6, lane = tid & 63;
    long r0 = (long)blockIdx.x * ROWS;
    for (int idx = tid; idx < ROWS * 32; idx += 512) {
        int r = idx >> 5, k4 = (idx & 31) * 4;
        float4 v = *(const float4*)&at[(r0 + r) * DBI + k4];
        X[r][k4 + 0] = f2bf(v.x); X[r][k4 + 1] = f2bf(v.y);
        X[r][k4 + 2] = f2bf(v.z); X[r][k4 + 3] = f2bf(v.w);
    }
    if (tid < ROWS) {
        long g = r0 + tid;
        s_b[tid] = (int)(g / NF);
        float tc = tcont[g];
        float t0 = tc * ((float)TSW / 3000.0f);
        int lo0 = (int)t0; if (lo0 > TSW - 2) lo0 = TSW - 2; if (lo0 < 0) lo0 = 0;
        s_lo0[tid] = lo0; s_w0[tid] = t0 - (float)lo0;
        float t1 = tc * ((float)TS1 / 3000.0f);
        int lo1 = (int)t1; if (lo1 > TS1 - 2) lo1 = TS1 - 2; if (lo1 < 0) lo1 = 0;
        s_lo1[tid] = lo1; s_w1[tid] = t1 - (float)lo1;
    }
    __syncthreads();
    int mrow = lane & 15, quad = lane >> 4;
    // ---- Phase 1: film GEMM (gamma+beta) + interp/FiLM epilogue -> X[:,128:512] bf16
    for (int nt = wave; nt < 24; nt += 8) {
        f32x4 ag0 = {0,0,0,0}, ag1 = {0,0,0,0}, ab0 = {0,0,0,0}, ab1 = {0,0,0,0};
        #pragma unroll
        for (int kt = 0; kt < 4; ++kt) {
            bf16x8 a0 = *(const bf16x8*)&X[mrow][kt * 32 + quad * 8];
            bf16x8 a1 = *(const bf16x8*)&X[16 + mrow][kt * 32 + quad * 8];
            bf16x8 bg = *(const bf16x8*)&Wg[(((nt * 4 + kt) * 64) + lane) * 8];
            bf16x8 bb = *(const bf16x8*)&Wb[(((nt * 4 + kt) * 64) + lane) * 8];
            ag0 = __builtin_amdgcn_mfma_f32_16x16x32_bf16(a0, bg, ag0, 0, 0, 0);
            ag1 = __builtin_amdgcn_mfma_f32_16x16x32_bf16(a1, bg, ag1, 0, 0, 0);
            ab0 = __builtin_amdgcn_mfma_f32_16x16x32_bf16(a0, bb, ab0, 0, 0, 0);
            ab1 = __builtin_amdgcn_mfma_f32_16x16x32_bf16(a1, bb, ab1, 0, 0, 0);
        }
        int c = nt * 16 + mrow;
        bool sel = c >= DSW;
        int cc = sel ? c - DSW : c;
        const float* S = sel ? src1 : src0;
        int Ts = sel ? TS1 : TSW;
        float gb = gbias[c], bbv = bbias[c];
        #pragma unroll
        for (int m = 0; m < 2; ++m) {
            #pragma unroll
            for (int q = 0; q < 4; ++q) {
                int r = m * 16 + quad * 4 + q;
                int b = s_b[r];
                int lo = sel ? s_lo1[r] : s_lo0[r];
                float w = sel ? s_w1[r] : s_w0[r];
                const float* Sp = S + ((long)b * Ts + lo) * DSW + cc;
                float pv = (1.0f - w) * Sp[0] + w * Sp[DSW];
                float gv = (m ? ag1[q] : ag0[q]) + gb;
                float bv = (m ? ab1[q] : ab0[q]) + bbv;
                X[r][128 + c] = f2bf(gv * pv + bv);
            }
        }
    }
    __syncthreads();
    // ---- Phase 2: embs[32,512] = X[32,512] @ W2 + bias2 ; wave owns 4 n-tiles
    f32x4 acc0[4], acc1[4];
    #pragma unroll
    for (int n = 0; n < 4; ++n) { acc0[n] = (f32x4){0,0,0,0}; acc1[n] = (f32x4){0,0,0,0}; }
    for (int kt = 0; kt < 16; ++kt) {
        bf16x8 a0 = *(const bf16x8*)&X[mrow][kt * 32 + quad * 8];
        bf16x8 a1 = *(const bf16x8*)&X[16 + mrow][kt * 32 + quad * 8];
        #pragma unroll
        for (int n = 0; n < 4; ++n) {
            int nt = wave * 4 + n;
            bf16x8 bfv = *(const bf16x8*)&W2[((nt * 16 + kt) * 64 + lane) * 8];
            acc0[n] = __builtin_amdgcn_mfma_f32_16x16x32_bf16(a0, bfv, acc0[n], 0, 0, 0);
            acc1[n] = __builtin_amdgcn_mfma_f32_16x16x32_bf16(a1, bfv, acc1[n], 0, 0, 0);
        }
    }
    #pragma unroll
    for (int n = 0; n < 4; ++n) {
        int cbase = (wave * 4 + n) * 16 + mrow;
        float bv = bias2[cbase];
        #pragma unroll
        for (int q = 0; q < 4; ++q) {
            embs[(r0 + quad * 4 + q) * DMODEL + cbase] = acc0[n][q] + bv;
            embs[(r0 + 16 + quad * 4 + q) * DMODEL + cbase] = acc1[n][q] + bv;
        }
    }
}

extern "C" void kernel_launch(void* const* d_in, const int* in_sizes, int n_in,
                              void* d_out, int out_size, void* d_ws, size_t ws_size,
                              hipStream_t stream)
{
    const float* fs     = (const float*)d_in[0];
    const float* src0   = (const float*)d_in[1];
    const float* src1   = (const float*)d_in[2];
    const int*   tlen   = (const int*)d_in[3];
    const float* conv_w = (const float*)d_in[4];
    const float* ln_g   = (const float*)d_in[5];
    const float* ln_b   = (const float*)d_in[6];
    const float* wp_w   = (const float*)d_in[7];
    const float* wp_b   = (const float*)d_in[8];
    const float* f0w    = (const float*)d_in[9];
    const float* f0b    = (const float*)d_in[10];
    const float* f1w    = (const float*)d_in[11];
    const float* f1b    = (const float*)d_in[12];
    const float* tw     = (const float*)d_in[13];
    const float* tb     = (const float*)d_in[14];
    const float* aw     = (const float*)d_in[15];
    const float* apb    = (const float*)d_in[16];
    const float* bw     = (const float*)d_in[17];
    const float* bpb    = (const float*)d_in[18];

    float* embs  = (float*)d_out;
    float* alpha = embs + (long)BQ * NF * DMODEL;
    float* qtyo  = alpha + (long)BQ * TBI;

    char* ws = (char*)d_ws;
    size_t off = 0;
    float*  at     = (float*)(ws + off);  off += 9830400;
    float2* c2     = (float2*)(ws + off); off += 1536000;
    float*  tcont  = (float*)(ws + off);  off += 76800;
    float2* params = (float2*)(ws + off); off += 512;
    float*  qtyb   = (float*)(ws + off);  off += 256;
    unsigned short* Wg = (unsigned short*)(ws + off); off += 98304;
    unsigned short* Wb = (unsigned short*)(ws + off); off += 98304;
    unsigned short* W2 = (unsigned short*)(ws + off); off += 524288;
    float* gbias = (float*)(ws + off); off += 1536;
    float* bbias = (float*)(ws + off); off += 1536;
    float* bias2 = (float*)(ws + off); off += 2048;

    hipMemsetAsync(at, 0, (size_t)BQ * NF * DBI * sizeof(float), stream);
    k_prep<<<1216, 256, 0, stream>>>(f0w, f1w, tw, aw, bw, Wg, Wb, W2);
    k_prepb<<<1, 512, 0, stream>>>(f0b, f1b, tb, apb, bpb, gbias, bbias, bias2);
    k_alpha2<<<(BQ * TBI) / 8, 256, 0, stream>>>(fs, conv_w, ln_g, ln_b, wp_w, wp_b, alpha);
    k_scan2<<<BQ, 1024, 0, stream>>>(alpha, tlen, params, qtyb, c2, tcont);
    k_qty<<<1, 64, 0, stream>>>(qtyb, qtyo);
    k_cif2<<<512, 256, 0, stream>>>(fs, c2, params, at);
    k_emb4<<<(BQ * NF) / ROWS, 512, 0, stream>>>(at, tcont, src0, src1,
                                                 Wg, Wb, W2, gbias, bbias, bias2, embs);
}

// Round 5
// 275.217 us; speedup vs baseline: 1.1976x; 1.0807x over previous
//
#include <hip/hip_runtime.h>
#include <math.h>

#define BQ 64
#define TBI 3000
#define DBI 128
#define TSW 375
#define TS1 188
#define DSW 192
#define NF 300
#define DMODEL 512
#define EPSLN 1e-5f

typedef __bf16 bf16x8 __attribute__((ext_vector_type(8)));
typedef float f32x4 __attribute__((ext_vector_type(4)));

__device__ __forceinline__ unsigned short f2bf(float f) {
    unsigned u = __float_as_uint(f);
    unsigned r = (u + 0x7FFFu + ((u >> 16) & 1u)) >> 16;
    return (unsigned short)r;
}

// ---------------- Kernel A: conv->LN->dot->sigmoid => alpha [B,T]; 2 rows/wave, float4 loads
__global__ __launch_bounds__(256) void k_alpha2(
    const float* __restrict__ fs, const float* __restrict__ conv_w,
    const float* __restrict__ ln_g, const float* __restrict__ ln_b,
    const float* __restrict__ wp_w, const float* __restrict__ wp_b,
    float* __restrict__ alpha_out)
{
    int wave = threadIdx.x >> 6, lane = threadIdx.x & 63;
    int l = lane & 31;
    long g = (long)blockIdx.x * 8 + wave * 2 + (lane >> 5);
    const float* row = fs + g * DBI;
    float4 f  = *(const float4*)&row[4 * l];
    float4 cw = *(const float4*)&conv_w[4 * l];
    float4 x; x.x = f.x * cw.x; x.y = f.y * cw.y; x.z = f.z * cw.z; x.w = f.w * cw.w;
    float s = x.x + x.y + x.z + x.w;
    for (int m = 16; m >= 1; m >>= 1) s += __shfl_xor(s, m, 64);
    float mu = s * (1.0f / 128.0f);
    float4 d; d.x = x.x - mu; d.y = x.y - mu; d.z = x.z - mu; d.w = x.w - mu;
    float q = d.x * d.x + d.y * d.y + d.z * d.z + d.w * d.w;
    for (int m = 16; m >= 1; m >>= 1) q += __shfl_xor(q, m, 64);
    float var = q * (1.0f / 128.0f);
    float rs = rsqrtf(var + EPSLN);
    float4 lg = *(const float4*)&ln_g[4 * l];
    float4 lb = *(const float4*)&ln_b[4 * l];
    float4 wp = *(const float4*)&wp_w[4 * l];
    float z = (d.x * rs * lg.x + lb.x) * wp.x + (d.y * rs * lg.y + lb.y) * wp.y
            + (d.z * rs * lg.z + lb.z) * wp.z + (d.w * rs * lg.w + lb.w) * wp.w;
    for (int m = 16; m >= 1; m >>= 1) z += __shfl_xor(z, m, 64);
    z += wp_b[0];
    float a = 4.0f / (1.0f + expf(-z));
    if (l == 0) alpha_out[g] = a;
}

// ---------------- Kernel B: sums (f64) + scan + searchsorted + ff store + qty atomic
__global__ __launch_bounds__(1024) void k_scan3(
    const float* __restrict__ alpha, const int* __restrict__ tlen,
    float2* __restrict__ params, float* __restrict__ qtyo,
    float2* __restrict__ c2, float* __restrict__ tcont, int* __restrict__ ffout)
{
    __shared__ float2 sc[TBI];
    __shared__ float2 part[2][1024];
    __shared__ double red[1024];
    int b = blockIdx.x, tid = threadIdx.x;
    const float* ar = alpha + (long)b * TBI;
    double s = 0.0;
    for (int t = tid; t < TBI; t += 1024) s += (double)ar[t];
    red[tid] = s; __syncthreads();
    for (int d = 512; d >= 1; d >>= 1) { if (tid < d) red[tid] += red[tid + d]; __syncthreads(); }
    double sum_a = red[0]; __syncthreads();
    double tgt = (double)tlen[b];
    double sa = sum_a < 1e-8 ? 1e-8 : sum_a;
    float r = (float)(tgt / sa);
    double s2 = 0.0;
    for (int t = tid; t < TBI; t += 1024) s2 += (double)(ar[t] * r);
    red[tid] = s2; __syncthreads();
    for (int d = 512; d >= 1; d >>= 1) { if (tid < d) red[tid] += red[tid + d]; __syncthreads(); }
    float sum_cif = (float)red[0];
    float cs = ceilf(sum_cif); if (cs < 1.0f) cs = 1.0f;
    float thr = sum_cif / cs;
    float rthr = 1.0f / thr;
    if (tid == 0) {
        params[b] = make_float2(r, thr);
        atomicAdd(qtyo, (float)fabs(sum_a - tgt) * (1.0f / (float)BQ));
    }
    int base = tid * 3;
    float2 run = make_float2(0.f, 0.f);
    if (base < TBI) {
        for (int j = 0; j < 3; ++j) {
            int t = base + j;
            float ac = ar[t] * r;
            run.x += ac * rthr; run.y += ac;
            sc[t] = run;
        }
    }
    part[0][tid] = (base < TBI) ? run : make_float2(0.f, 0.f);
    __syncthreads();
    int srcb = 0;
    for (int d = 1; d < 1024; d <<= 1) {
        float2 v = part[srcb][tid];
        if (tid >= d) { float2 u = part[srcb][tid - d]; v.x += u.x; v.y += u.y; }
        part[srcb ^ 1][tid] = v;
        srcb ^= 1;
        __syncthreads();
    }
    if (base < TBI && tid > 0) {
        float2 off = part[srcb][tid - 1];
        for (int j = 0; j < 3; ++j) { sc[base + j].x += off.x; sc[base + j].y += off.y; }
    }
    __syncthreads();
    for (int t = tid; t < TBI; t += 1024) {
        float ac = ar[t] * r;
        c2[(long)b * TBI + t] = make_float2(sc[t].x, ac);
    }
    if (tid < NF) {
        float v = (float)(tid + 1) * thr;
        int lo = 0, hi = TBI;
        while (lo < hi) { int mid = (lo + hi) >> 1; if (sc[mid].y < v) lo = mid + 1; else hi = mid; }
        int ff = lo; if (ff > TBI - 1) ff = TBI - 1;
        ffout[b * NF + tid] = ff;
        int tl = ff - 1; if (tl < 0) tl = 0;
        float cum_at = sc[tl].y;
        float a_at = ar[ff] * r;
        if (a_at < 1e-8f) a_at = 1e-8f;
        float tc = (float)tl + (v - cum_at) / a_at;
        tc = fminf(fmaxf(tc, 0.0f), (float)(TBI - 1));
        tcont[b * NF + tid] = tc;
    }
}

// ---------------- Kernel D: CIF, token-owned partition — no atomics, no memset
#define TPW 3   // tokens per wave; 100 waves/batch
__global__ __launch_bounds__(256) void k_cif3(
    const float* __restrict__ fs, const float2* __restrict__ c2,
    const int* __restrict__ ffA, const float2* __restrict__ params,
    float* __restrict__ at)
{
    int wid = threadIdx.x >> 6, lane = threadIdx.x & 63;
    int wg = blockIdx.x * 4 + wid;          // 0..6399
    int b = wg / 100, slot = wg - b * 100;
    int j0 = slot * TPW;
    const int* ffb = ffA + b * NF;
    int t0 = (j0 == 0) ? 0 : ffb[j0 - 1];
    int tE = (slot == 99) ? (TBI - 1) : ffb[j0 + TPW - 1];
    float thr = params[b].y;
    float rthr = 1.0f / thr;
    const float2* cb = c2 + (long)b * TBI;
    const float* fb = fs + (long)b * TBI * DBI;
    float* ab = at + (long)b * NF * DBI;
    int nw = j0;                            // next owned token to write
    int cur = -1;
    float a0 = 0.f, a1 = 0.f;
    #define FLUSH() do { \
        if (cur >= j0 && cur < j0 + TPW) { \
            while (nw < cur) { *(float2*)&ab[nw * DBI + 2 * lane] = make_float2(0.f, 0.f); ++nw; } \
            *(float2*)&ab[cur * DBI + 2 * lane] = make_float2(a0, a1); nw = cur + 1; \
        } } while (0)
    for (int t = t0; t <= tE; ++t) {
        float2 v = cb[t];
        float2 h = *(const float2*)&fb[(long)t * DBI + 2 * lane];
        float c = v.x, ac = v.y;
        float av = ac * rthr;
        float prev = c - av;
        float kp = floorf(prev), kc = floorf(c);
        bool fired = kc > kp;
        float w_lo = fired ? (kp + 1.0f - prev) * thr : ac;
        float w_hi = fired ? (c - kc) * thr : 0.0f;
        int ip = (int)kp; if (ip > NF - 1) ip = NF - 1; if (ip < 0) ip = 0;
        int ic = (int)kc; if (ic > NF - 1) ic = NF - 1; if (ic < 0) ic = 0;
        if (ip != cur) { FLUSH(); cur = ip; a0 = 0.f; a1 = 0.f; }
        a0 += w_lo * h.x; a1 += w_lo * h.y;
        if (fired) {
            if (ic != cur) { FLUSH(); cur = ic; a0 = 0.f; a1 = 0.f; }
            a0 += w_hi * h.x; a1 += w_hi * h.y;
        }
    }
    FLUSH();
    while (nw < j0 + TPW) { *(float2*)&ab[nw * DBI + 2 * lane] = make_float2(0.f, 0.f); ++nw; }
    #undef FLUSH
}

// ---------------- Prep: weight swizzle (bf16 B-fragments) + biases + qtyo zero
__global__ __launch_bounds__(256) void k_prep2(
    const float* __restrict__ f0w, const float* __restrict__ f1w,
    const float* __restrict__ tw, const float* __restrict__ aw, const float* __restrict__ bw,
    const float* __restrict__ f0b, const float* __restrict__ f1b,
    const float* __restrict__ tb, const float* __restrict__ apb, const float* __restrict__ bpb,
    unsigned short* __restrict__ Wg, unsigned short* __restrict__ Wb,
    unsigned short* __restrict__ W2,
    float* __restrict__ gbias, float* __restrict__ bbias, float* __restrict__ bias2,
    float* __restrict__ qtyo)
{
    if (blockIdx.x == 1216) {
        for (int c = threadIdx.x; c < 512; c += 256) {
            if (c < 384) {
                gbias[c] = c < 192 ? f0b[c] : f1b[c - 192];
                bbias[c] = c < 192 ? f0b[c + 192] : f1b[c - 192 + 192];
            }
            bias2[c] = tb[c] + apb[c] + bpb[c];
        }
        if (threadIdx.x == 0) qtyo[0] = 0.f;
        return;
    }
    int i = blockIdx.x * 256 + threadIdx.x;
    if (i < 49152) {                       // film gamma/beta: K=128 (KT=4), N=384 (NT=24)
        int j = i & 7, lane = (i >> 3) & 63, kt = (i >> 9) & 3, nt = i >> 11;
        int k = kt * 32 + (lane >> 4) * 8 + j;
        int n = nt * 16 + (lane & 15);
        float g, b;
        if (n < 192) { g = f0w[k * 384 + n];         b = f0w[k * 384 + n + 192]; }
        else         { g = f1w[k * 384 + (n - 192)]; b = f1w[k * 384 + (n - 192) + 192]; }
        Wg[i] = f2bf(g); Wb[i] = f2bf(b);
    } else {                               // W2 stacked [tw;aw;bw]: K=512 (KT=16), N=512 (NT=32)
        int ii = i - 49152;
        int j = ii & 7, lane = (ii >> 3) & 63, kt = (ii >> 9) & 15, nt = ii >> 13;
        int k = kt * 32 + (lane >> 4) * 8 + j;
        int n = nt * 16 + (lane & 15);
        float v;
        if (k < 128)      v = tw[k * 512 + n];
        else if (k < 320) v = aw[(k - 128) * 512 + n];
        else              v = bw[(k - 320) * 512 + n];
        W2[ii] = f2bf(v);
    }
}

// ---------------- Kernel E (MFMA): FiLM + interp + projections; ROWS=16, 1200 blocks
#define EROWS 16
__global__ __launch_bounds__(512, 6) void k_emb5(
    const float* __restrict__ at, const float* __restrict__ tcont,
    const float* __restrict__ src0, const float* __restrict__ src1,
    const unsigned short* __restrict__ Wg, const unsigned short* __restrict__ Wb,
    const unsigned short* __restrict__ W2,
    const float* __restrict__ gbias, const float* __restrict__ bbias,
    const float* __restrict__ bias2, float* __restrict__ embs)
{
    __shared__ __align__(16) unsigned short X[EROWS][520];
    __shared__ float s_w0[EROWS], s_w1[EROWS];
    __shared__ int s_lo0[EROWS], s_lo1[EROWS], s_b[EROWS];
    int tid = threadIdx.x;
    int wave = tid >> 6, lane = tid & 63;
    long r0 = (long)blockIdx.x * EROWS;
    {
        int r = tid >> 5, k4 = (tid & 31) * 4;     // 512 threads = 16 rows x 32 groups
        float4 v = *(const float4*)&at[(r0 + r) * DBI + k4];
        X[r][k4 + 0] = f2bf(v.x); X[r][k4 + 1] = f2bf(v.y);
        X[r][k4 + 2] = f2bf(v.z); X[r][k4 + 3] = f2bf(v.w);
    }
    if (tid < EROWS) {
        long g = r0 + tid;
        s_b[tid] = (int)(g / NF);
        float tc = tcont[g];
        float t0 = tc * ((float)TSW / 3000.0f);
        int lo0 = (int)t0; if (lo0 > TSW - 2) lo0 = TSW - 2; if (lo0 < 0) lo0 = 0;
        s_lo0[tid] = lo0; s_w0[tid] = t0 - (float)lo0;
        float t1 = tc * ((float)TS1 / 3000.0f);
        int lo1 = (int)t1; if (lo1 > TS1 - 2) lo1 = TS1 - 2; if (lo1 < 0) lo1 = 0;
        s_lo1[tid] = lo1; s_w1[tid] = t1 - (float)lo1;
    }
    __syncthreads();
    int mrow = lane & 15, quad = lane >> 4;
    // ---- Phase 1: film GEMM (gamma+beta) + interp/FiLM epilogue -> X[:,128:512] bf16
    for (int nt = wave; nt < 24; nt += 8) {
        f32x4 ag = {0,0,0,0}, ab = {0,0,0,0};
        #pragma unroll
        for (int kt = 0; kt < 4; ++kt) {
            bf16x8 a = *(const bf16x8*)&X[mrow][kt * 32 + quad * 8];
            bf16x8 bg = *(const bf16x8*)&Wg[(((nt * 4 + kt) * 64) + lane) * 8];
            bf16x8 bb = *(const bf16x8*)&Wb[(((nt * 4 + kt) * 64) + lane) * 8];
            ag = __builtin_amdgcn_mfma_f32_16x16x32_bf16(a, bg, ag, 0, 0, 0);
            ab = __builtin_amdgcn_mfma_f32_16x16x32_bf16(a, bb, ab, 0, 0, 0);
        }
        int c = nt * 16 + mrow;
        bool sel = c >= DSW;
        int cc = sel ? c - DSW : c;
        const float* S = sel ? src1 : src0;
        int Ts = sel ? TS1 : TSW;
        float gb = gbias[c], bbv = bbias[c];
        #pragma unroll
        for (int q = 0; q < 4; ++q) {
            int r = quad * 4 + q;
            int b = s_b[r];
            int lo = sel ? s_lo1[r] : s_lo0[r];
            float w = sel ? s_w1[r] : s_w0[r];
            const float* Sp = S + ((long)b * Ts + lo) * DSW + cc;
            float pv = (1.0f - w) * Sp[0] + w * Sp[DSW];
            X[r][128 + c] = f2bf((ag[q] + gb) * pv + (ab[q] + bbv));
        }
    }
    __syncthreads();
    // ---- Phase 2: embs[16,512] = X[16,512] @ W2 + bias2 ; wave owns 4 n-tiles
    f32x4 acc[4];
    #pragma unroll
    for (int n = 0; n < 4; ++n) acc[n] = (f32x4){0, 0, 0, 0};
    for (int kt = 0; kt < 16; ++kt) {
        bf16x8 a = *(const bf16x8*)&X[mrow][kt * 32 + quad * 8];
        #pragma unroll
        for (int n = 0; n < 4; ++n) {
            int nt = wave * 4 + n;
            bf16x8 bfv = *(const bf16x8*)&W2[((nt * 16 + kt) * 64 + lane) * 8];
            acc[n] = __builtin_amdgcn_mfma_f32_16x16x32_bf16(a, bfv, acc[n], 0, 0, 0);
        }
    }
    #pragma unroll
    for (int n = 0; n < 4; ++n) {
        int cbase = (wave * 4 + n) * 16 + mrow;
        float bv = bias2[cbase];
        #pragma unroll
        for (int q = 0; q < 4; ++q)
            embs[(r0 + quad * 4 + q) * DMODEL + cbase] = acc[n][q] + bv;
    }
}

extern "C" void kernel_launch(void* const* d_in, const int* in_sizes, int n_in,
                              void* d_out, int out_size, void* d_ws, size_t ws_size,
                              hipStream_t stream)
{
    const float* fs     = (const float*)d_in[0];
    const float* src0   = (const float*)d_in[1];
    const float* src1   = (const float*)d_in[2];
    const int*   tlen   = (const int*)d_in[3];
    const float* conv_w = (const float*)d_in[4];
    const float* ln_g   = (const float*)d_in[5];
    const float* ln_b   = (const float*)d_in[6];
    const float* wp_w   = (const float*)d_in[7];
    const float* wp_b   = (const float*)d_in[8];
    const float* f0w    = (const float*)d_in[9];
    const float* f0b    = (const float*)d_in[10];
    const float* f1w    = (const float*)d_in[11];
    const float* f1b    = (const float*)d_in[12];
    const float* tw     = (const float*)d_in[13];
    const float* tb     = (const float*)d_in[14];
    const float* aw     = (const float*)d_in[15];
    const float* apb    = (const float*)d_in[16];
    const float* bw     = (const float*)d_in[17];
    const float* bpb    = (const float*)d_in[18];

    float* embs  = (float*)d_out;
    float* alpha = embs + (long)BQ * NF * DMODEL;
    float* qtyo  = alpha + (long)BQ * TBI;

    char* ws = (char*)d_ws;
    size_t off = 0;
    float*  at     = (float*)(ws + off);  off += 9830400;
    float2* c2     = (float2*)(ws + off); off += 1536000;
    float*  tcont  = (float*)(ws + off);  off += 76800;
    int*    ffA    = (int*)(ws + off);    off += 76800;
    float2* params = (float2*)(ws + off); off += 512;
    unsigned short* Wg = (unsigned short*)(ws + off); off += 98304;
    unsigned short* Wb = (unsigned short*)(ws + off); off += 98304;
    unsigned short* W2 = (unsigned short*)(ws + off); off += 524288;
    float* gbias = (float*)(ws + off); off += 1536;
    float* bbias = (float*)(ws + off); off += 1536;
    float* bias2 = (float*)(ws + off); off += 2048;

    k_prep2<<<1217, 256, 0, stream>>>(f0w, f1w, tw, aw, bw, f0b, f1b, tb, apb, bpb,
                                      Wg, Wb, W2, gbias, bbias, bias2, qtyo);
    k_alpha2<<<(BQ * TBI) / 8, 256, 0, stream>>>(fs, conv_w, ln_g, ln_b, wp_w, wp_b, alpha);
    k_scan3<<<BQ, 1024, 0, stream>>>(alpha, tlen, params, qtyo, c2, tcont, ffA);
    k_cif3<<<(BQ * 100) / 4, 256, 0, stream>>>(fs, c2, ffA, params, at);
    k_emb5<<<(BQ * NF) / EROWS, 512, 0, stream>>>(at, tcont, src0, src1,
                                                  Wg, Wb, W2, gbias, bbias, bias2, embs);
}